// Round 1
// baseline (206.561 us; speedup 1.0000x reference)
//
#include <hip/hip_runtime.h>
#include <cstddef>

#define T_STEPS 1024
#define BATCH   32768
#define G1      50
#define H1      32
#define G2      20

__device__ __forceinline__ float softplus_f(float x) {
    // jax.nn.softplus = logaddexp(x, 0) = max(x,0) + log1p(exp(-|x|))
    float e = __expf(-fabsf(x));
    return fmaxf(x, 0.0f) + __logf(1.0f + e);
}

// One thread per time step: full 2-layer RBF-KAN -> softplus -> betas[t]
__global__ __launch_bounds__(64) void beta_kernel(
    const float* __restrict__ t_steps,
    const float* __restrict__ grid1,      // [50]
    const float* __restrict__ spline_w1,  // [50, 32] row-major (g, j)
    const float* __restrict__ base_w1,    // [32, 1]
    const float* __restrict__ grid2,      // [20]
    const float* __restrict__ spline_w2,  // [640, 1]  index j*20+g
    const float* __restrict__ base_w2,    // [1, 32]
    float* __restrict__ betas)            // [1024] out
{
    int t = blockIdx.x * 64 + threadIdx.x;
    if (t >= T_STEPS) return;
    float x = t_steps[t];

    // Layer 1: h[j] = x*base_w1[j] + sum_g exp(-10*(x-grid1[g])^2) * w1[g][j]
    float h[H1];
    #pragma unroll
    for (int j = 0; j < H1; ++j) h[j] = x * base_w1[j];
    for (int g = 0; g < G1; ++g) {
        float d = x - grid1[g];
        float e = __expf(-10.0f * d * d);
        #pragma unroll
        for (int j = 0; j < H1; ++j)
            h[j] = fmaf(e, spline_w1[g * H1 + j], h[j]);
    }

    // Layer 2: pre = sum_j h[j]*base_w2[j] + sum_{j,g} exp(-10*(h[j]-grid2[g])^2)*w2[j*20+g]
    float a0 = 0.f, a1 = 0.f, a2 = 0.f, a3 = 0.f;
    #pragma unroll
    for (int j = 0; j < H1; j += 4) {
        a0 = fmaf(h[j + 0], base_w2[j + 0], a0);
        a1 = fmaf(h[j + 1], base_w2[j + 1], a1);
        a2 = fmaf(h[j + 2], base_w2[j + 2], a2);
        a3 = fmaf(h[j + 3], base_w2[j + 3], a3);
    }
    for (int j = 0; j < H1; ++j) {
        float hj = h[j];
        #pragma unroll
        for (int g = 0; g < G2; g += 4) {
            float d0 = hj - grid2[g + 0];
            float d1 = hj - grid2[g + 1];
            float d2 = hj - grid2[g + 2];
            float d3 = hj - grid2[g + 3];
            a0 = fmaf(__expf(-10.f * d0 * d0), spline_w2[j * G2 + g + 0], a0);
            a1 = fmaf(__expf(-10.f * d1 * d1), spline_w2[j * G2 + g + 1], a1);
            a2 = fmaf(__expf(-10.f * d2 * d2), spline_w2[j * G2 + g + 2], a2);
            a3 = fmaf(__expf(-10.f * d3 * d3), spline_w2[j * G2 + g + 3], a3);
        }
    }
    float pre = (a0 + a1) + (a2 + a3);
    betas[t] = softplus_f(pre);
}

// One thread per batch element; sequential over T. Stores are the roofline
// (128 MiB). 256 blocks x 128 threads -> all 256 CUs participate in writeback.
__global__ __launch_bounds__(128) void scan_kernel(
    const float* __restrict__ t_steps,
    const float* __restrict__ initial_I,
    const float* __restrict__ gamma_param,
    const float* __restrict__ betas,
    float* __restrict__ out)   // [T, B]
{
    __shared__ float sbeta[T_STEPS];
    for (int i = threadIdx.x; i < T_STEPS; i += 128)
        sbeta[i] = betas[i];
    __syncthreads();

    int b = blockIdx.x * 128 + threadIdx.x;
    float I = initial_I[b];
    float S = 1.0f - I;
    float gamma = softplus_f(gamma_param[0]);
    float dt = t_steps[1] - t_steps[0];
    float* outp = out + b;

    #pragma unroll 8
    for (int t = 0; t < T_STEPS; ++t) {
        float beta = sbeta[t];
        float ninf = beta * S * I;                    // new_inf = beta*S*I
        float In = fmaf(dt, fmaf(-gamma, I, ninf), I); // I + dt*(ninf - gamma*I)
        I = fminf(fmaxf(In, 0.0f), 5.0f);             // clip(.., 0, 5)
        float Sn = fmaf(-dt, ninf, S);                // S - dt*ninf
        S = fminf(fmaxf(Sn, 0.0f), 5.0f);
        __builtin_nontemporal_store(I, outp + (size_t)t * BATCH);
    }
}

extern "C" void kernel_launch(void* const* d_in, const int* in_sizes, int n_in,
                              void* d_out, int out_size, void* d_ws, size_t ws_size,
                              hipStream_t stream) {
    const float* t_steps     = (const float*)d_in[0];
    const float* initial_I   = (const float*)d_in[1];
    const float* grid1       = (const float*)d_in[2];
    const float* spline_w1   = (const float*)d_in[3];
    const float* base_w1     = (const float*)d_in[4];
    const float* grid2       = (const float*)d_in[5];
    const float* spline_w2   = (const float*)d_in[6];
    const float* base_w2     = (const float*)d_in[7];
    const float* gamma_param = (const float*)d_in[8];
    float* out   = (float*)d_out;
    float* betas = (float*)d_ws;   // 1024 floats of scratch

    beta_kernel<<<T_STEPS / 64, 64, 0, stream>>>(
        t_steps, grid1, spline_w1, base_w1, grid2, spline_w2, base_w2, betas);
    scan_kernel<<<BATCH / 128, 128, 0, stream>>>(
        t_steps, initial_I, gamma_param, betas, out);
}

// Round 2
// 170.331 us; speedup vs baseline: 1.2127x; 1.2127x over previous
//
#include <hip/hip_runtime.h>
#include <cstddef>

#define T_STEPS 1024
#define BATCH   32768
#define G1      50
#define H1      32
#define G2      20

__device__ __forceinline__ float softplus_f(float x) {
    // jax.nn.softplus = max(x,0) + log1p(exp(-|x|))
    float e = __expf(-fabsf(x));
    return fmaxf(x, 0.0f) + __logf(1.0f + e);
}

// One BLOCK (1 wave, 64 lanes) per time step t.
//  phase 1: lanes 0..49 compute e_g = exp(-10 (x-grid1[g])^2)  -> LDS
//  phase 2: lanes 0..31 compute h[j] = x*bw1[j] + sum_g e_g*w1[g][j] -> LDS
//  phase 3: 640 (j,g) layer-2 terms split 10 per lane + base terms, wave-reduce
__global__ __launch_bounds__(64) void beta_kernel(
    const float* __restrict__ t_steps,
    const float* __restrict__ grid1,      // [50]
    const float* __restrict__ spline_w1,  // [50, 32] (g, j)
    const float* __restrict__ base_w1,    // [32]
    const float* __restrict__ grid2,      // [20]
    const float* __restrict__ spline_w2,  // [640]  index j*20+g
    const float* __restrict__ base_w2,    // [32]
    float* __restrict__ betas)            // [1024] out
{
    __shared__ float se[G1];
    __shared__ float sh[H1];

    const int t    = blockIdx.x;
    const int lane = threadIdx.x;
    const float x  = t_steps[t];

    if (lane < G1) {
        float d = x - grid1[lane];
        se[lane] = __expf(-10.0f * d * d);
    }
    __syncthreads();

    if (lane < H1) {
        float acc = x * base_w1[lane];
        #pragma unroll
        for (int g = 0; g < G1; ++g)
            acc = fmaf(se[g], spline_w1[g * H1 + lane], acc);  // se[g]: LDS broadcast
        sh[lane] = acc;
    }
    __syncthreads();

    // layer 2: 640 spline terms, 10 per lane; plus base term for lanes < 32
    float acc = 0.0f;
    #pragma unroll
    for (int k = 0; k < 10; ++k) {
        int p = lane + 64 * k;        // 0..639
        int j = p / G2;
        int g = p - j * G2;
        float d = sh[j] - grid2[g];
        acc = fmaf(__expf(-10.0f * d * d), spline_w2[p], acc);
    }
    if (lane < H1) acc = fmaf(sh[lane], base_w2[lane], acc);

    // 64-lane butterfly reduce
    #pragma unroll
    for (int ofs = 32; ofs >= 1; ofs >>= 1)
        acc += __shfl_xor(acc, ofs, 64);

    if (lane == 0) betas[t] = softplus_f(acc);
}

// One thread per batch element; sequential over T. 256 blocks x 128 threads
// = 512 waves = 2 waves/CU on all 256 CUs; each wave emits 256 B per ~30-cyc
// dependency chain, above the 10.2 B/cyc/CU HBM write drain -> BW-bound.
__global__ __launch_bounds__(128) void scan_kernel(
    const float* __restrict__ t_steps,
    const float* __restrict__ initial_I,
    const float* __restrict__ gamma_param,
    const float* __restrict__ betas,
    float* __restrict__ out)   // [T, B]
{
    __shared__ float sbeta[T_STEPS];
    #pragma unroll
    for (int i = 0; i < T_STEPS / 128; ++i)
        sbeta[threadIdx.x + i * 128] = betas[threadIdx.x + i * 128];
    __syncthreads();

    const int b = blockIdx.x * 128 + threadIdx.x;
    float I = initial_I[b];
    float S = 1.0f - I;
    const float gamma = softplus_f(gamma_param[0]);
    const float dt = t_steps[1] - t_steps[0];
    float* outp = out + b;

    #pragma unroll 8
    for (int t = 0; t < T_STEPS; ++t) {
        float beta = sbeta[t];
        float ninf = beta * S * I;                      // new_inf = beta*S*I
        float In = fmaf(dt, fmaf(-gamma, I, ninf), I);  // I + dt*(ninf - gamma*I)
        I = fminf(fmaxf(In, 0.0f), 5.0f);
        float Sn = fmaf(-dt, ninf, S);                  // S - dt*new_inf
        S = fminf(fmaxf(Sn, 0.0f), 5.0f);
        __builtin_nontemporal_store(I, outp + (size_t)t * BATCH);
    }
}

extern "C" void kernel_launch(void* const* d_in, const int* in_sizes, int n_in,
                              void* d_out, int out_size, void* d_ws, size_t ws_size,
                              hipStream_t stream) {
    const float* t_steps     = (const float*)d_in[0];
    const float* initial_I   = (const float*)d_in[1];
    const float* grid1       = (const float*)d_in[2];
    const float* spline_w1   = (const float*)d_in[3];
    const float* base_w1     = (const float*)d_in[4];
    const float* grid2       = (const float*)d_in[5];
    const float* spline_w2   = (const float*)d_in[6];
    const float* base_w2     = (const float*)d_in[7];
    const float* gamma_param = (const float*)d_in[8];
    float* out   = (float*)d_out;
    float* betas = (float*)d_ws;   // 1024 floats of scratch

    beta_kernel<<<T_STEPS, 64, 0, stream>>>(
        t_steps, grid1, spline_w1, base_w1, grid2, spline_w2, base_w2, betas);
    scan_kernel<<<BATCH / 128, 128, 0, stream>>>(
        t_steps, initial_I, gamma_param, betas, out);
}

// Round 3
// 158.431 us; speedup vs baseline: 1.3038x; 1.0751x over previous
//
#include <hip/hip_runtime.h>
#include <cstddef>

#define T_STEPS 1024
#define BATCH   32768
#define G1      50
#define H1      32
#define G2      20

__device__ __forceinline__ float softplus_f(float x) {
    // jax.nn.softplus = max(x,0) + log1p(exp(-|x|))
    float e = __expf(-fabsf(x));
    return fmaxf(x, 0.0f) + __logf(1.0f + e);
}

// One BLOCK (1 wave, 64 lanes) per time step t. Writes a[t] = dt * beta(t).
__global__ __launch_bounds__(64) void beta_kernel(
    const float* __restrict__ t_steps,
    const float* __restrict__ grid1,      // [50]
    const float* __restrict__ spline_w1,  // [50, 32] (g, j)
    const float* __restrict__ base_w1,    // [32]
    const float* __restrict__ grid2,      // [20]
    const float* __restrict__ spline_w2,  // [640]  index j*20+g
    const float* __restrict__ base_w2,    // [32]
    float* __restrict__ a_out)            // [1024] out: dt*beta
{
    __shared__ float se[G1];
    __shared__ float sh[H1];

    const int t    = blockIdx.x;
    const int lane = threadIdx.x;
    const float x  = t_steps[t];

    if (lane < G1) {
        float d = x - grid1[lane];
        se[lane] = __expf(-10.0f * d * d);
    }
    __syncthreads();

    if (lane < H1) {
        float acc = x * base_w1[lane];
        #pragma unroll
        for (int g = 0; g < G1; ++g)
            acc = fmaf(se[g], spline_w1[g * H1 + lane], acc);  // LDS broadcast
        sh[lane] = acc;
    }
    __syncthreads();

    // layer 2: 640 spline terms, 10 per lane; plus base term for lanes < 32
    float acc = 0.0f;
    #pragma unroll
    for (int k = 0; k < 10; ++k) {
        int p = lane + 64 * k;        // 0..639
        int j = p / G2;
        int g = p - j * G2;
        float d = sh[j] - grid2[g];
        acc = fmaf(__expf(-10.0f * d * d), spline_w2[p], acc);
    }
    if (lane < H1) acc = fmaf(sh[lane], base_w2[lane], acc);

    // 64-lane butterfly reduce
    #pragma unroll
    for (int ofs = 32; ofs >= 1; ofs >>= 1)
        acc += __shfl_xor(acc, ofs, 64);

    if (lane == 0) {
        float dt = t_steps[1] - t_steps[0];
        a_out[t] = dt * softplus_f(acc);
    }
}

// One thread per batch element; sequential over T.
// Update rewritten as I' = clip(I * (c + a*S)), S' = clip(S * (1 - a*I)),
// a = dt*beta (precomputed), c = 1 - dt*gamma -> 16-cyc critical path/iter.
// 256 blocks x 128 threads = 2 waves/CU on all 256 CUs; offered ~32 B/cyc/CU
// >> 10.2 B/cyc/CU HBM drain -> write-BW bound (~21 us for 128 MiB).
__global__ __launch_bounds__(128) void scan_kernel(
    const float* __restrict__ t_steps,
    const float* __restrict__ initial_I,
    const float* __restrict__ gamma_param,
    const float* __restrict__ a_in,   // [1024] dt*beta
    float* __restrict__ out)          // [T, B]
{
    __shared__ float4 sa4[T_STEPS / 4];
    {
        const float4* g4 = (const float4*)a_in;
        #pragma unroll
        for (int i = 0; i < T_STEPS / 4 / 128; ++i)
            sa4[threadIdx.x + i * 128] = g4[threadIdx.x + i * 128];
    }
    __syncthreads();

    const int b = blockIdx.x * 128 + threadIdx.x;
    float I = initial_I[b];
    float S = 1.0f - I;
    const float gamma = softplus_f(gamma_param[0]);
    const float dt = t_steps[1] - t_steps[0];
    const float c = fmaf(-dt, gamma, 1.0f);   // 1 - dt*gamma
    float* outp = out + b;

    // 16 steps per body: 4x ds_read_b128 hoisted, then 16 short chains + stores
    #pragma unroll 1
    for (int tb = 0; tb < T_STEPS; tb += 16) {
        float4 q[4];
        #pragma unroll
        for (int k = 0; k < 4; ++k) q[k] = sa4[tb / 4 + k];
        const float* av = (const float*)q;
        #pragma unroll
        for (int k = 0; k < 16; ++k) {
            float a  = av[k];
            float f  = fmaf(a, S, c);        // c + a*S        (uses old S)
            float u  = fmaf(-a, I, 1.0f);    // 1 - a*I        (uses old I)
            float In = I * f;                // I + dt*(b*S*I - g*I)
            float Sn = S * u;                // S - dt*b*S*I
            I = fminf(fmaxf(In, 0.0f), 5.0f);
            S = fminf(fmaxf(Sn, 0.0f), 5.0f);
            outp[(size_t)(tb + k) * BATCH] = I;
        }
    }
}

extern "C" void kernel_launch(void* const* d_in, const int* in_sizes, int n_in,
                              void* d_out, int out_size, void* d_ws, size_t ws_size,
                              hipStream_t stream) {
    const float* t_steps     = (const float*)d_in[0];
    const float* initial_I   = (const float*)d_in[1];
    const float* grid1       = (const float*)d_in[2];
    const float* spline_w1   = (const float*)d_in[3];
    const float* base_w1     = (const float*)d_in[4];
    const float* grid2       = (const float*)d_in[5];
    const float* spline_w2   = (const float*)d_in[6];
    const float* base_w2     = (const float*)d_in[7];
    const float* gamma_param = (const float*)d_in[8];
    float* out = (float*)d_out;
    float* a_t = (float*)d_ws;   // 1024 floats: dt*beta(t)

    beta_kernel<<<T_STEPS, 64, 0, stream>>>(
        t_steps, grid1, spline_w1, base_w1, grid2, spline_w2, base_w2, a_t);
    scan_kernel<<<BATCH / 128, 128, 0, stream>>>(
        t_steps, initial_I, gamma_param, a_t, out);
}